// Round 5
// baseline (154.581 us; speedup 1.0000x reference)
//
#include <hip/hip_runtime.h>

namespace {
constexpr int DEPTH    = 11;
constexpr int IN_W     = 768;
constexpr int LEAF_W   = 16;
constexpr int OUT_W    = 768;
constexpr int N_NODES  = (1 << DEPTH) - 1;   // 2047
constexpr int N_LEAVES = (1 << DEPTH);       // 2048
constexpr int BATCH    = 8192;
}

// async global -> LDS, 16 B per lane (lds dest = wave-uniform base + lane*16)
__device__ __forceinline__ void gload_lds16(const void* g, void* l) {
    __builtin_amdgcn_global_load_lds(
        (const __attribute__((address_space(1))) unsigned int*)g,
        (__attribute__((address_space(3))) unsigned int*)l, 16, 0, 0);
}

// ---------------- Kernel A: tree routing (one wave per sample) ----------------
// fp64 accumulation keeps decision-boundary error (~3e-8) far below the fp32
// numpy reference's own rounding (~1e-7) -> routing decisions match.
__global__ __launch_bounds__(256) void fff_route(
    const float* __restrict__ x,
    const float* __restrict__ nw,
    const float* __restrict__ nb,
    int* __restrict__ leaf_of,
    int* __restrict__ rank_of,
    int* __restrict__ cnt)
{
    const int lane = threadIdx.x & 63;
    const int s    = (int)((blockIdx.x * blockDim.x + threadIdx.x) >> 6);

    const float* xp = x + (size_t)s * IN_W + lane * 12;
    const float4 xv0 = *(const float4*)(xp + 0);
    const float4 xv1 = *(const float4*)(xp + 4);
    const float4 xv2 = *(const float4*)(xp + 8);
    const float xs[12] = {xv0.x, xv0.y, xv0.z, xv0.w,
                          xv1.x, xv1.y, xv1.z, xv1.w,
                          xv2.x, xv2.y, xv2.z, xv2.w};

    int node = 0;
    #pragma unroll 1
    for (int d = 0; d < DEPTH; ++d) {
        const float* wp = nw + (size_t)node * IN_W + lane * 12;
        const float4 a0 = *(const float4*)(wp + 0);
        const float4 a1 = *(const float4*)(wp + 4);
        const float4 a2 = *(const float4*)(wp + 8);
        const float wa[12] = {a0.x, a0.y, a0.z, a0.w,
                              a1.x, a1.y, a1.z, a1.w,
                              a2.x, a2.y, a2.z, a2.w};
        double acc = 0.0;
        #pragma unroll
        for (int j = 0; j < 12; ++j)
            acc = fma((double)wa[j], (double)xs[j], acc);
        #pragma unroll
        for (int off = 32; off > 0; off >>= 1)
            acc += __shfl_xor(acc, off, 64);
        const double score = acc + (double)nb[node];
        node = 2 * node + 1 + (score >= 0.0 ? 1 : 0);
    }
    const int leaf = node - N_NODES;

    if (lane == 0) {
        leaf_of[s] = leaf;
        rank_of[s] = atomicAdd(&cnt[leaf], 1);
    }
}

// ---------------- Kernel B: exclusive scan of 2048 counts (one wave) ----------------
__global__ void fff_scan(const int* __restrict__ cnt, int* __restrict__ off) {
    const int lane = threadIdx.x & 63;        // launched with 64 threads
    const int base = lane * (N_LEAVES / 64);  // 32 leaves per lane
    int local[N_LEAVES / 64];
    int sum = 0;
    #pragma unroll
    for (int i = 0; i < N_LEAVES / 64; ++i) { local[i] = cnt[base + i]; sum += local[i]; }
    int v = sum;
    #pragma unroll
    for (int d = 1; d < 64; d <<= 1) {
        int u = __shfl_up(v, d, 64);
        if (lane >= d) v += u;
    }
    int run = v - sum;
    #pragma unroll
    for (int i = 0; i < N_LEAVES / 64; ++i) { off[base + i] = run; run += local[i]; }
}

// ---------------- Kernel C: scatter samples into leaf-sorted order ----------------
__global__ __launch_bounds__(256) void fff_scatter(
    const int* __restrict__ leaf_of, const int* __restrict__ rank_of,
    const int* __restrict__ off, int* __restrict__ sorted)
{
    const int s = blockIdx.x * blockDim.x + threadIdx.x;
    if (s < BATCH) sorted[off[leaf_of[s]] + rank_of[s]] = s;
}

// ------- Kernel D: one block per leaf; weights bulk-streamed into LDS -------
// Stage w1 (48 KB, XOR-swizzled image) -> layer1 for <=16 samples (wave each
// handles <=4) -> restage w2 (48 KB, linear) into the SAME buffer -> layer2.
// 48 KB LDS => 3 blocks/CU resident: compute overlaps neighbor blocks' stages.
__global__ __launch_bounds__(256, 3) void fff_mlp_lds(
    const float* __restrict__ x,
    const float* __restrict__ w1,
    const float* __restrict__ b1,
    const float* __restrict__ w2,
    const int* __restrict__ cnt,
    const int* __restrict__ off,
    const int* __restrict__ sorted,
    float* __restrict__ out)
{
    __shared__ float s_w[IN_W * LEAF_W];   // 48 KB, reused for w1 then w2

    const int leaf = blockIdx.x;
    const int n    = cnt[leaf];
    if (n == 0) return;
    const int o0   = off[leaf];
    const int wv   = threadIdx.x >> 6;
    const int L    = threadIdx.x & 63;

    // per-lane byte offsets for staging (16 B per lane within each 1 KB block)
    const int lin16 = L << 4;
    const int swz16 = lin16 ^ (((L >> 3) & 3) << 4);   // w1: swizzled source
    // layer-1 read swizzle for this lane (same involution, read side)
    const int dsw = ((L >> 1) & 3) << 4;

    const char* w1g = (const char*)(w1 + (size_t)leaf * (IN_W * LEAF_W));
    const char* w2g = (const char*)(w2 + (size_t)leaf * (LEAF_W * OUT_W));
    const float* b1g = b1 + (size_t)leaf * LEAF_W;

    for (int base0 = 0; base0 < n; base0 += 16) {
        const int m = min(16, n - base0);

        // ---- stage w1 (swizzled image): 48 instr total, 12 per wave ----
        #pragma unroll
        for (int j = 0; j < 12; ++j) {
            const int blk = (j * 4 + wv) * 1024;
            gload_lds16(w1g + blk + swz16, (char*)s_w + blk);
        }
        asm volatile("s_waitcnt vmcnt(0)" ::: "memory");
        __syncthreads();

        // ---- layer 1: wave wv handles chunk-local samples wv, wv+4, wv+8, wv+12 ----
        float hreg[4][LEAF_W];
        int   sidx[4];
        #pragma unroll
        for (int smp = 0; smp < 4; ++smp) {
            const int il = wv + smp * 4;
            if (il < m) {
                const int s = sorted[o0 + base0 + il];
                sidx[smp] = s;
                const float* xg = x + (size_t)s * IN_W;
                float xs[12];
                #pragma unroll
                for (int k = 0; k < 12; ++k) xs[k] = xg[64 * k + L];

                float h[LEAF_W];
                #pragma unroll
                for (int l = 0; l < LEAF_W; ++l) h[l] = 0.f;
                #pragma unroll
                for (int k = 0; k < 12; ++k) {
                    const float xk = xs[k];
                    const char* rowp = (const char*)s_w + (size_t)(L + 64 * k) * 64;
                    const float4 w0 = *(const float4*)(rowp + (0  ^ dsw));
                    const float4 wq = *(const float4*)(rowp + (16 ^ dsw));
                    const float4 w2v= *(const float4*)(rowp + (32 ^ dsw));
                    const float4 w3 = *(const float4*)(rowp + (48 ^ dsw));
                    h[0]  = fmaf(xk, w0.x, h[0]);  h[1]  = fmaf(xk, w0.y, h[1]);
                    h[2]  = fmaf(xk, w0.z, h[2]);  h[3]  = fmaf(xk, w0.w, h[3]);
                    h[4]  = fmaf(xk, wq.x, h[4]);  h[5]  = fmaf(xk, wq.y, h[5]);
                    h[6]  = fmaf(xk, wq.z, h[6]);  h[7]  = fmaf(xk, wq.w, h[7]);
                    h[8]  = fmaf(xk, w2v.x, h[8]); h[9]  = fmaf(xk, w2v.y, h[9]);
                    h[10] = fmaf(xk, w2v.z, h[10]);h[11] = fmaf(xk, w2v.w, h[11]);
                    h[12] = fmaf(xk, w3.x, h[12]); h[13] = fmaf(xk, w3.y, h[13]);
                    h[14] = fmaf(xk, w3.z, h[14]); h[15] = fmaf(xk, w3.w, h[15]);
                }
                // butterfly reduce across 64 lanes (identical result on all lanes)
                #pragma unroll
                for (int l = 0; l < LEAF_W; ++l) {
                    float v = h[l];
                    #pragma unroll
                    for (int o2 = 32; o2 > 0; o2 >>= 1) v += __shfl_xor(v, o2, 64);
                    hreg[smp][l] = fmaxf(v + b1g[l], 0.f);
                }
            }
        }
        __syncthreads();   // all layer-1 reads of s_w complete

        // ---- restage w2 (linear image) into the same buffer ----
        #pragma unroll
        for (int j = 0; j < 12; ++j) {
            const int blk = (j * 4 + wv) * 1024;
            gload_lds16(w2g + blk + lin16, (char*)s_w + blk);
        }
        asm volatile("s_waitcnt vmcnt(0)" ::: "memory");
        __syncthreads();

        // ---- layer 2: lane owns 12 output cols (48 B at col 12L) ----
        #pragma unroll
        for (int smp = 0; smp < 4; ++smp) {
            const int il = wv + smp * 4;
            if (il < m) {
                float oa[12];
                #pragma unroll
                for (int j = 0; j < 12; ++j) oa[j] = 0.f;
                #pragma unroll
                for (int l = 0; l < LEAF_W; ++l) {
                    const float hl = hreg[smp][l];
                    const char* rowp = (const char*)s_w + (size_t)l * (OUT_W * 4) + 48 * L;
                    const float4 r0 = *(const float4*)(rowp + 0);
                    const float4 r1 = *(const float4*)(rowp + 16);
                    const float4 r2 = *(const float4*)(rowp + 32);
                    oa[0] = fmaf(hl, r0.x, oa[0]);  oa[1]  = fmaf(hl, r0.y, oa[1]);
                    oa[2] = fmaf(hl, r0.z, oa[2]);  oa[3]  = fmaf(hl, r0.w, oa[3]);
                    oa[4] = fmaf(hl, r1.x, oa[4]);  oa[5]  = fmaf(hl, r1.y, oa[5]);
                    oa[6] = fmaf(hl, r1.z, oa[6]);  oa[7]  = fmaf(hl, r1.w, oa[7]);
                    oa[8] = fmaf(hl, r2.x, oa[8]);  oa[9]  = fmaf(hl, r2.y, oa[9]);
                    oa[10]= fmaf(hl, r2.z, oa[10]); oa[11] = fmaf(hl, r2.w, oa[11]);
                }
                float* op = out + (size_t)sidx[smp] * OUT_W + 12 * L;
                *(float4*)(op + 0) = make_float4(oa[0], oa[1], oa[2],  oa[3]);
                *(float4*)(op + 4) = make_float4(oa[4], oa[5], oa[6],  oa[7]);
                *(float4*)(op + 8) = make_float4(oa[8], oa[9], oa[10], oa[11]);
            }
        }
        __syncthreads();   // protect s_w before next chunk's restage (rare)
    }
}

extern "C" void kernel_launch(void* const* d_in, const int* in_sizes, int n_in,
                              void* d_out, int out_size, void* d_ws, size_t ws_size,
                              hipStream_t stream) {
    const float* x  = (const float*)d_in[0];
    const float* nw = (const float*)d_in[1];
    const float* nb = (const float*)d_in[2];
    const float* w1 = (const float*)d_in[3];
    const float* b1 = (const float*)d_in[4];
    const float* w2 = (const float*)d_in[5];
    float* o        = (float*)d_out;

    // workspace (ints): cnt[2048] | off[2048] | leaf[8192] | rank[8192] | sorted[8192]
    int* cnt    = (int*)d_ws;
    int* off    = cnt + N_LEAVES;
    int* leaf   = off + N_LEAVES;
    int* rank   = leaf + BATCH;
    int* sorted = rank + BATCH;

    hipMemsetAsync(cnt, 0, N_LEAVES * sizeof(int), stream);

    fff_route  <<<dim3(BATCH / 4),  dim3(256), 0, stream>>>(x, nw, nb, leaf, rank, cnt);
    fff_scan   <<<dim3(1),          dim3(64),  0, stream>>>(cnt, off);
    fff_scatter<<<dim3(BATCH/256),  dim3(256), 0, stream>>>(leaf, rank, off, sorted);
    fff_mlp_lds<<<dim3(N_LEAVES),   dim3(256), 0, stream>>>(x, w1, b1, w2, cnt, off, sorted, o);
}

// Round 6
// 120.232 us; speedup vs baseline: 1.2857x; 1.2857x over previous
//
#include <hip/hip_runtime.h>

namespace {
constexpr int DEPTH    = 11;
constexpr int IN_W     = 768;
constexpr int LEAF_W   = 16;
constexpr int OUT_W    = 768;
constexpr int N_NODES  = (1 << DEPTH) - 1;   // 2047
constexpr int N_LEAVES = (1 << DEPTH);       // 2048
constexpr int BATCH    = 8192;
}

// ---------------- Kernel A: tree routing (one wave per sample) ----------------
// fp64 accumulation keeps decision-boundary error (~3e-8) far below the fp32
// numpy reference's own rounding (~1e-7) -> routing decisions match.
__global__ __launch_bounds__(256) void fff_route(
    const float* __restrict__ x,
    const float* __restrict__ nw,
    const float* __restrict__ nb,
    int* __restrict__ leaf_of,
    int* __restrict__ rank_of,
    int* __restrict__ cnt)
{
    const int lane = threadIdx.x & 63;
    const int s    = (int)((blockIdx.x * blockDim.x + threadIdx.x) >> 6);

    const float* xp = x + (size_t)s * IN_W + lane * 12;
    const float4 xv0 = *(const float4*)(xp + 0);
    const float4 xv1 = *(const float4*)(xp + 4);
    const float4 xv2 = *(const float4*)(xp + 8);
    const float xs[12] = {xv0.x, xv0.y, xv0.z, xv0.w,
                          xv1.x, xv1.y, xv1.z, xv1.w,
                          xv2.x, xv2.y, xv2.z, xv2.w};

    int node = 0;
    #pragma unroll 1
    for (int d = 0; d < DEPTH; ++d) {
        const float* wp = nw + (size_t)node * IN_W + lane * 12;
        const float4 a0 = *(const float4*)(wp + 0);
        const float4 a1 = *(const float4*)(wp + 4);
        const float4 a2 = *(const float4*)(wp + 8);
        const float wa[12] = {a0.x, a0.y, a0.z, a0.w,
                              a1.x, a1.y, a1.z, a1.w,
                              a2.x, a2.y, a2.z, a2.w};
        double acc = 0.0;
        #pragma unroll
        for (int j = 0; j < 12; ++j)
            acc = fma((double)wa[j], (double)xs[j], acc);
        #pragma unroll
        for (int off = 32; off > 0; off >>= 1)
            acc += __shfl_xor(acc, off, 64);
        const double score = acc + (double)nb[node];
        node = 2 * node + 1 + (score >= 0.0 ? 1 : 0);
    }
    const int leaf = node - N_NODES;

    if (lane == 0) {
        leaf_of[s] = leaf;
        rank_of[s] = atomicAdd(&cnt[leaf], 1);
    }
}

// ---------------- Kernel B: exclusive scan of 2048 counts (one wave) ----------------
__global__ void fff_scan(const int* __restrict__ cnt, int* __restrict__ off) {
    const int lane = threadIdx.x & 63;        // launched with 64 threads
    const int base = lane * (N_LEAVES / 64);  // 32 leaves per lane
    int local[N_LEAVES / 64];
    int sum = 0;
    #pragma unroll
    for (int i = 0; i < N_LEAVES / 64; ++i) { local[i] = cnt[base + i]; sum += local[i]; }
    int v = sum;
    #pragma unroll
    for (int d = 1; d < 64; d <<= 1) {
        int u = __shfl_up(v, d, 64);
        if (lane >= d) v += u;
    }
    int run = v - sum;
    #pragma unroll
    for (int i = 0; i < N_LEAVES / 64; ++i) { off[base + i] = run; run += local[i]; }
}

// ---------------- Kernel C: scatter samples into leaf-sorted order ----------------
__global__ __launch_bounds__(256) void fff_scatter(
    const int* __restrict__ leaf_of, const int* __restrict__ rank_of,
    const int* __restrict__ off,
    int* __restrict__ sorted, int* __restrict__ leaf_sorted)
{
    const int s = blockIdx.x * blockDim.x + threadIdx.x;
    if (s < BATCH) {
        const int lf = leaf_of[s];
        const int i  = off[lf] + rank_of[s];
        sorted[i]      = s;
        leaf_sorted[i] = lf;
    }
}

// ---- helpers for explicit load pipelining (all indices compile-time) ----
__device__ __forceinline__ void ld2rows(const float* p, int r, float4 (&D)[8]) {
    #pragma unroll
    for (int q = 0; q < 8; ++q)
        D[q] = *(const float4*)(p + (size_t)r * LEAF_W + q * 4);
}
__device__ __forceinline__ void fma2rows(const float4 (&D)[8], float x0, float x1,
                                         float (&h)[LEAF_W]) {
    const float* d = (const float*)&D[0];
    #pragma unroll
    for (int l = 0; l < 16; ++l) h[l] = fmaf(x0, d[l], h[l]);
    #pragma unroll
    for (int l = 0; l < 16; ++l) h[l] = fmaf(x1, d[16 + l], h[l]);
}
__device__ __forceinline__ void ld4rows(const float* p, int base, float4 (&D)[12]) {
    #pragma unroll
    for (int j = 0; j < 4; ++j)
        #pragma unroll
        for (int q = 0; q < 3; ++q)
            D[j * 3 + q] = *(const float4*)(p + (size_t)(base + j) * OUT_W + q * 4);
}
__device__ __forceinline__ void fma4rows(const float4 (&D)[12], const float* h4,
                                         float (&oa)[12]) {
    #pragma unroll
    for (int j = 0; j < 4; ++j) {
        const float hl = h4[j];
        const float* d = (const float*)&D[j * 3];
        #pragma unroll
        for (int t = 0; t < 12; ++t) oa[t] = fmaf(hl, d[t], oa[t]);
    }
}

// ---------- Kernel D: leaf MLP, one wave per sorted position, pipelined ----------
// Explicit double-buffered load windows (8 / 12 float4 in flight) + many waves
// (VGPR cap 168 -> ~12 waves/CU) = deep per-CU outstanding-load queue.
// XCD-bijective block swizzle keeps same-leaf neighborhoods on one XCD's L2.
__global__ __launch_bounds__(256, 3) void fff_mlp3(
    const float* __restrict__ x,
    const float* __restrict__ w1,
    const float* __restrict__ b1,
    const float* __restrict__ w2,
    const int* __restrict__ sorted,
    const int* __restrict__ leaf_sorted,
    float* __restrict__ out)
{
    const int lane = threadIdx.x & 63;
    // hardware: blockIdx % 8 selects the XCD. Map so virtual-block order is
    // contiguous per XCD: XCD k owns virtual blocks [k*256, (k+1)*256).
    const int vb   = (int)((blockIdx.x & 7) * (gridDim.x >> 3) + (blockIdx.x >> 3));
    const int i    = vb * 4 + (int)(threadIdx.x >> 6);
    const int s    = sorted[i];
    const int leaf = leaf_sorted[i];

    const float* xp = x + (size_t)s * IN_W + lane * 12;
    const float4 xv0 = *(const float4*)(xp + 0);
    const float4 xv1 = *(const float4*)(xp + 4);
    const float4 xv2 = *(const float4*)(xp + 8);
    const float xs[12] = {xv0.x, xv0.y, xv0.z, xv0.w,
                          xv1.x, xv1.y, xv1.z, xv1.w,
                          xv2.x, xv2.y, xv2.z, xv2.w};

    // ---- layer 1: lane owns 12 w1 rows; 2-row double-buffered pipeline ----
    const float* w1p = w1 + (size_t)leaf * (IN_W * LEAF_W) + (size_t)lane * 12 * LEAF_W;
    float h[LEAF_W];
    #pragma unroll
    for (int l = 0; l < LEAF_W; ++l) h[l] = 0.f;

    float4 A[8], B[8];
    ld2rows(w1p, 0, A);
    ld2rows(w1p, 2, B);  fma2rows(A, xs[0],  xs[1],  h);
    ld2rows(w1p, 4, A);  fma2rows(B, xs[2],  xs[3],  h);
    ld2rows(w1p, 6, B);  fma2rows(A, xs[4],  xs[5],  h);
    ld2rows(w1p, 8, A);  fma2rows(B, xs[6],  xs[7],  h);
    ld2rows(w1p, 10, B); fma2rows(A, xs[8],  xs[9],  h);
    fma2rows(B, xs[10], xs[11], h);

    // butterfly reduce across 64 lanes (identical result on all lanes)
    #pragma unroll
    for (int l = 0; l < LEAF_W; ++l) {
        float v = h[l];
        #pragma unroll
        for (int o2 = 32; o2 > 0; o2 >>= 1) v += __shfl_xor(v, o2, 64);
        h[l] = v;
    }
    const float* b1p = b1 + (size_t)leaf * LEAF_W;
    #pragma unroll
    for (int l = 0; l < LEAF_W; ++l) h[l] = fmaxf(h[l] + b1p[l], 0.f);

    // ---- layer 2: lane owns 12 output cols; 4-row double-buffered pipeline ----
    const float* w2p = w2 + (size_t)leaf * (LEAF_W * OUT_W) + lane * 12;
    float oa[12];
    #pragma unroll
    for (int j = 0; j < 12; ++j) oa[j] = 0.f;

    float4 C[12], D[12];
    ld4rows(w2p, 0, C);
    ld4rows(w2p, 4, D);   fma4rows(C, &h[0],  oa);
    ld4rows(w2p, 8, C);   fma4rows(D, &h[4],  oa);
    ld4rows(w2p, 12, D);  fma4rows(C, &h[8],  oa);
    fma4rows(D, &h[12], oa);

    float* op = out + (size_t)s * OUT_W + lane * 12;
    *(float4*)(op + 0) = make_float4(oa[0], oa[1], oa[2],  oa[3]);
    *(float4*)(op + 4) = make_float4(oa[4], oa[5], oa[6],  oa[7]);
    *(float4*)(op + 8) = make_float4(oa[8], oa[9], oa[10], oa[11]);
}

extern "C" void kernel_launch(void* const* d_in, const int* in_sizes, int n_in,
                              void* d_out, int out_size, void* d_ws, size_t ws_size,
                              hipStream_t stream) {
    const float* x  = (const float*)d_in[0];
    const float* nw = (const float*)d_in[1];
    const float* nb = (const float*)d_in[2];
    const float* w1 = (const float*)d_in[3];
    const float* b1 = (const float*)d_in[4];
    const float* w2 = (const float*)d_in[5];
    float* o        = (float*)d_out;

    // workspace (ints): cnt[2048] | off[2048] | leaf[8192] | rank[8192] | sorted[8192] | leafs[8192]
    int* cnt    = (int*)d_ws;
    int* off    = cnt + N_LEAVES;
    int* leaf   = off + N_LEAVES;
    int* rank   = leaf + BATCH;
    int* sorted = rank + BATCH;
    int* leafs  = sorted + BATCH;

    hipMemsetAsync(cnt, 0, N_LEAVES * sizeof(int), stream);

    fff_route  <<<dim3(BATCH / 4), dim3(256), 0, stream>>>(x, nw, nb, leaf, rank, cnt);
    fff_scan   <<<dim3(1),         dim3(64),  0, stream>>>(cnt, off);
    fff_scatter<<<dim3(BATCH/256), dim3(256), 0, stream>>>(leaf, rank, off, sorted, leafs);
    fff_mlp3   <<<dim3(BATCH / 4), dim3(256), 0, stream>>>(x, w1, b1, w2, sorted, leafs, o);
}

// Round 8
// 102.998 us; speedup vs baseline: 1.5008x; 1.1673x over previous
//
#include <hip/hip_runtime.h>

namespace {
constexpr int DEPTH    = 11;
constexpr int IN_W     = 768;
constexpr int LEAF_W   = 16;
constexpr int OUT_W    = 768;
constexpr int N_NODES  = (1 << DEPTH) - 1;   // 2047
constexpr int N_LEAVES = (1 << DEPTH);       // 2048
constexpr int BATCH    = 8192;
}

// ---------------- Kernel A: tree routing (one wave per sample) ----------------
// fp64 accumulation keeps decision-boundary error (~3e-8) far below the fp32
// numpy reference's own rounding (~1e-7) -> routing decisions match.
__global__ __launch_bounds__(256) void fff_route(
    const float* __restrict__ x,
    const float* __restrict__ nw,
    const float* __restrict__ nb,
    int* __restrict__ leaf_of,
    int* __restrict__ rank_of,
    int* __restrict__ cnt)
{
    const int lane = threadIdx.x & 63;
    const int s    = (int)((blockIdx.x * blockDim.x + threadIdx.x) >> 6);

    const float* xp = x + (size_t)s * IN_W + lane * 12;
    const float4 xv0 = *(const float4*)(xp + 0);
    const float4 xv1 = *(const float4*)(xp + 4);
    const float4 xv2 = *(const float4*)(xp + 8);
    const float xs[12] = {xv0.x, xv0.y, xv0.z, xv0.w,
                          xv1.x, xv1.y, xv1.z, xv1.w,
                          xv2.x, xv2.y, xv2.z, xv2.w};

    int node = 0;
    #pragma unroll 1
    for (int d = 0; d < DEPTH; ++d) {
        const float* wp = nw + (size_t)node * IN_W + lane * 12;
        const float4 a0 = *(const float4*)(wp + 0);
        const float4 a1 = *(const float4*)(wp + 4);
        const float4 a2 = *(const float4*)(wp + 8);
        const float wa[12] = {a0.x, a0.y, a0.z, a0.w,
                              a1.x, a1.y, a1.z, a1.w,
                              a2.x, a2.y, a2.z, a2.w};
        double acc = 0.0;
        #pragma unroll
        for (int j = 0; j < 12; ++j)
            acc = fma((double)wa[j], (double)xs[j], acc);
        #pragma unroll
        for (int off = 32; off > 0; off >>= 1)
            acc += __shfl_xor(acc, off, 64);
        const double score = acc + (double)nb[node];
        node = 2 * node + 1 + (score >= 0.0 ? 1 : 0);
    }
    const int leaf = node - N_NODES;

    if (lane == 0) {
        leaf_of[s] = leaf;
        rank_of[s] = atomicAdd(&cnt[leaf], 1);
    }
}

// ---------------- Kernel B: exclusive scan of 2048 counts (one wave) ----------------
__global__ void fff_scan(const int* __restrict__ cnt, int* __restrict__ off) {
    const int lane = threadIdx.x & 63;        // launched with 64 threads
    const int base = lane * (N_LEAVES / 64);  // 32 leaves per lane
    int local[N_LEAVES / 64];
    int sum = 0;
    #pragma unroll
    for (int i = 0; i < N_LEAVES / 64; ++i) { local[i] = cnt[base + i]; sum += local[i]; }
    int v = sum;
    #pragma unroll
    for (int d = 1; d < 64; d <<= 1) {
        int u = __shfl_up(v, d, 64);
        if (lane >= d) v += u;
    }
    int run = v - sum;
    #pragma unroll
    for (int i = 0; i < N_LEAVES / 64; ++i) { off[base + i] = run; run += local[i]; }
}

// ---------------- Kernel C: scatter samples into leaf-sorted order ----------------
__global__ __launch_bounds__(256) void fff_scatter(
    const int* __restrict__ leaf_of, const int* __restrict__ rank_of,
    const int* __restrict__ off,
    int* __restrict__ sorted, int* __restrict__ leaf_sorted)
{
    const int s = blockIdx.x * blockDim.x + threadIdx.x;
    if (s < BATCH) {
        const int lf = leaf_of[s];
        const int i  = off[lf] + rank_of[s];
        sorted[i]      = s;
        leaf_sorted[i] = lf;
    }
}

// ---- inline-asm 16B load: dest VGPRs, per-lane voffset, uniform SGPR base ----
__device__ __forceinline__ void gl4(float4& d, unsigned voff, const float* sb) {
    asm volatile("global_load_dwordx4 %0, %1, %2"
                 : "=v"(d) : "v"(voff), "s"(sb));
}
// counted wait + scheduling fence (rule 18: FMAs must not hoist above the wait)
#define VMWAIT(N) do { asm volatile("s_waitcnt vmcnt(" #N ")"); \
                       __builtin_amdgcn_sched_barrier(0); } while (0)

__device__ __forceinline__ void fma_row16(float xk, const float4& a, const float4& b,
                                          const float4& c, const float4& d,
                                          float (&h)[LEAF_W]) {
    h[0] = fmaf(xk, a.x, h[0]);  h[1] = fmaf(xk, a.y, h[1]);
    h[2] = fmaf(xk, a.z, h[2]);  h[3] = fmaf(xk, a.w, h[3]);
    h[4] = fmaf(xk, b.x, h[4]);  h[5] = fmaf(xk, b.y, h[5]);
    h[6] = fmaf(xk, b.z, h[6]);  h[7] = fmaf(xk, b.w, h[7]);
    h[8] = fmaf(xk, c.x, h[8]);  h[9] = fmaf(xk, c.y, h[9]);
    h[10]= fmaf(xk, c.z, h[10]); h[11]= fmaf(xk, c.w, h[11]);
    h[12]= fmaf(xk, d.x, h[12]); h[13]= fmaf(xk, d.y, h[13]);
    h[14]= fmaf(xk, d.z, h[14]); h[15]= fmaf(xk, d.w, h[15]);
}
__device__ __forceinline__ void fma_row12(float hl, const float4& a, const float4& b,
                                          const float4& c, float (&oa)[12]) {
    oa[0] = fmaf(hl, a.x, oa[0]);  oa[1] = fmaf(hl, a.y, oa[1]);
    oa[2] = fmaf(hl, a.z, oa[2]);  oa[3] = fmaf(hl, a.w, oa[3]);
    oa[4] = fmaf(hl, b.x, oa[4]);  oa[5] = fmaf(hl, b.y, oa[5]);
    oa[6] = fmaf(hl, b.z, oa[6]);  oa[7] = fmaf(hl, b.w, oa[7]);
    oa[8] = fmaf(hl, c.x, oa[8]);  oa[9] = fmaf(hl, c.y, oa[9]);
    oa[10]= fmaf(hl, c.z, oa[10]); oa[11]= fmaf(hl, c.w, oa[11]);
}

// ------- Kernel D: wave-per-sorted-sample MLP, inline-asm pipelined loads -------
// Volatile asm loads keep a fixed issue order => deterministic vmcnt counting.
// Steady state: 16 loads (L1) / 12 loads (L2) in flight per wave; waits never
// drain to 0 mid-loop. L2's first 4 rows issue before the butterfly reduce so
// their latency hides under the shuffle chain (in-order completion => the
// inflated L1-tail waits below remain exact).
__global__ __launch_bounds__(256, 3) void fff_mlp_pipe(
    const float* __restrict__ x,
    const float* __restrict__ w1,
    const float* __restrict__ b1,
    const float* __restrict__ w2,
    const int* __restrict__ sorted,
    const int* __restrict__ leaf_sorted,
    float* __restrict__ out)
{
    const int lane = threadIdx.x & 63;
    // XCD-bijective swizzle (2048 blocks, 8 XCDs -> 256 contiguous vblocks each)
    const int vb   = (int)((blockIdx.x & 7) * (gridDim.x >> 3) + (blockIdx.x >> 3));
    const int i    = vb * 4 + (int)(threadIdx.x >> 6);
    const int s    = sorted[i];
    const int leaf = __builtin_amdgcn_readfirstlane(leaf_sorted[i]);

    const float* xp = x + (size_t)s * IN_W + lane * 12;
    const float4 xv0 = *(const float4*)(xp + 0);
    const float4 xv1 = *(const float4*)(xp + 4);
    const float4 xv2 = *(const float4*)(xp + 8);
    // pin all compiler-visible loads (scalar components -> one VGPR each):
    // their s_waitcnt lands HERE, not mid-pipeline
    asm volatile("" :: "v"(xv0.x), "v"(xv0.y), "v"(xv0.z), "v"(xv0.w),
                       "v"(xv1.x), "v"(xv1.y), "v"(xv1.z), "v"(xv1.w),
                       "v"(xv2.x), "v"(xv2.y), "v"(xv2.z), "v"(xv2.w),
                       "v"(s));
    const float xs[12] = {xv0.x, xv0.y, xv0.z, xv0.w,
                          xv1.x, xv1.y, xv1.z, xv1.w,
                          xv2.x, xv2.y, xv2.z, xv2.w};

    const float* w1b = w1 + (size_t)leaf * (IN_W * LEAF_W);   // uniform (SGPR)
    const float* w2b = w2 + (size_t)leaf * (LEAF_W * OUT_W);  // uniform (SGPR)

    // per-lane voffsets (bytes)
    const unsigned vA = (unsigned)(lane * 768);       // L1: lane's 12-row slab
    const unsigned vB = vA + 16, vC = vA + 32, vD = vA + 48;
    const unsigned u0 = (unsigned)(lane * 48);        // L2: lane's 12-col slice
    const unsigned u1 = u0 + 16, u2 = u0 + 32;

    float4 W[4][4];   // L1 window: 4 rows x 4 float4  (64 VGPR)
    float4 V[4][3];   // L2 window: 4 rows x 3 float4  (48 VGPR)
    float h[LEAF_W];
    #pragma unroll
    for (int l = 0; l < LEAF_W; ++l) h[l] = 0.f;

#define L1_LOAD(r) do { const float* sb = w1b + (r) * LEAF_W; \
    gl4(W[(r) & 3][0], vA, sb); gl4(W[(r) & 3][1], vB, sb); \
    gl4(W[(r) & 3][2], vC, sb); gl4(W[(r) & 3][3], vD, sb); } while (0)
#define L1_FMA(r) fma_row16(xs[(r)], W[(r)&3][0], W[(r)&3][1], W[(r)&3][2], W[(r)&3][3], h)
#define L2_LOAD(r) do { const float* sb = w2b + (r) * OUT_W; \
    gl4(V[(r) & 3][0], u0, sb); gl4(V[(r) & 3][1], u1, sb); \
    gl4(V[(r) & 3][2], u2, sb); } while (0)
#define L2_FMA(r) fma_row12(h[(r)], V[(r)&3][0], V[(r)&3][1], V[(r)&3][2], oa)

    // ---- layer 1: 12 rows, window 4 (16 loads in flight) ----
    L1_LOAD(0); L1_LOAD(1); L1_LOAD(2); L1_LOAD(3);
    VMWAIT(12); L1_FMA(0); L1_LOAD(4);
    VMWAIT(12); L1_FMA(1); L1_LOAD(5);
    VMWAIT(12); L1_FMA(2); L1_LOAD(6);
    VMWAIT(12); L1_FMA(3); L1_LOAD(7);
    VMWAIT(12); L1_FMA(4); L1_LOAD(8);
    VMWAIT(12); L1_FMA(5); L1_LOAD(9);
    VMWAIT(12); L1_FMA(6); L1_LOAD(10);
    VMWAIT(12); L1_FMA(7); L1_LOAD(11);
    // prefetch L2 rows 0..3 now; their latency hides under L1 tail + butterfly
    L2_LOAD(0); L2_LOAD(1); L2_LOAD(2); L2_LOAD(3);      // +12 outstanding
    VMWAIT(24); L1_FMA(8);       // 48+12 issued, need 36 done -> <=24 left
    VMWAIT(20); L1_FMA(9);
    VMWAIT(16); L1_FMA(10);
    VMWAIT(12); L1_FMA(11);      // all L1 consumed; 12 L2 loads still in flight

    // butterfly reduce across 64 lanes (identical result on all lanes)
    #pragma unroll
    for (int l = 0; l < LEAF_W; ++l) {
        float v = h[l];
        #pragma unroll
        for (int o2 = 32; o2 > 0; o2 >>= 1) v += __shfl_xor(v, o2, 64);
        h[l] = v;
    }
    const float* b1p = b1 + (size_t)leaf * LEAF_W;   // uniform -> SMEM path
    #pragma unroll
    for (int l = 0; l < LEAF_W; ++l) h[l] = fmaxf(h[l] + b1p[l], 0.f);

    float oa[12];
    #pragma unroll
    for (int j = 0; j < 12; ++j) oa[j] = 0.f;

    // ---- layer 2: 16 rows, window 4 (12 loads in flight) ----
    VMWAIT(9); L2_FMA(0);  L2_LOAD(4);
    VMWAIT(9); L2_FMA(1);  L2_LOAD(5);
    VMWAIT(9); L2_FMA(2);  L2_LOAD(6);
    VMWAIT(9); L2_FMA(3);  L2_LOAD(7);
    VMWAIT(9); L2_FMA(4);  L2_LOAD(8);
    VMWAIT(9); L2_FMA(5);  L2_LOAD(9);
    VMWAIT(9); L2_FMA(6);  L2_LOAD(10);
    VMWAIT(9); L2_FMA(7);  L2_LOAD(11);
    VMWAIT(9); L2_FMA(8);  L2_LOAD(12);
    VMWAIT(9); L2_FMA(9);  L2_LOAD(13);
    VMWAIT(9); L2_FMA(10); L2_LOAD(14);
    VMWAIT(9); L2_FMA(11); L2_LOAD(15);
    VMWAIT(9); L2_FMA(12);
    VMWAIT(6); L2_FMA(13);
    VMWAIT(3); L2_FMA(14);
    VMWAIT(0); L2_FMA(15);

    float* op = out + (size_t)s * OUT_W + lane * 12;
    *(float4*)(op + 0) = make_float4(oa[0], oa[1], oa[2],  oa[3]);
    *(float4*)(op + 4) = make_float4(oa[4], oa[5], oa[6],  oa[7]);
    *(float4*)(op + 8) = make_float4(oa[8], oa[9], oa[10], oa[11]);

#undef L1_LOAD
#undef L1_FMA
#undef L2_LOAD
#undef L2_FMA
}

extern "C" void kernel_launch(void* const* d_in, const int* in_sizes, int n_in,
                              void* d_out, int out_size, void* d_ws, size_t ws_size,
                              hipStream_t stream) {
    const float* x  = (const float*)d_in[0];
    const float* nw = (const float*)d_in[1];
    const float* nb = (const float*)d_in[2];
    const float* w1 = (const float*)d_in[3];
    const float* b1 = (const float*)d_in[4];
    const float* w2 = (const float*)d_in[5];
    float* o        = (float*)d_out;

    // workspace (ints): cnt[2048] | off[2048] | leaf[8192] | rank[8192] | sorted[8192] | leafs[8192]
    int* cnt    = (int*)d_ws;
    int* off    = cnt + N_LEAVES;
    int* leaf   = off + N_LEAVES;
    int* rank   = leaf + BATCH;
    int* sorted = rank + BATCH;
    int* leafs  = sorted + BATCH;

    (void)hipMemsetAsync(cnt, 0, N_LEAVES * sizeof(int), stream);

    fff_route   <<<dim3(BATCH / 4), dim3(256), 0, stream>>>(x, nw, nb, leaf, rank, cnt);
    fff_scan    <<<dim3(1),         dim3(64),  0, stream>>>(cnt, off);
    fff_scatter <<<dim3(BATCH/256), dim3(256), 0, stream>>>(leaf, rank, off, sorted, leafs);
    fff_mlp_pipe<<<dim3(BATCH / 4), dim3(256), 0, stream>>>(x, w1, b1, w2, sorted, leafs, o);
}